// Round 4
// baseline (85.245 us; speedup 1.0000x reference)
//
#include <hip/hip_runtime.h>

constexpr int A_TOTAL = 5456;
constexpr int BATCH = 16;
constexpr int NUM_CLASSES = 80;
constexpr int NUM_CH = NUM_CLASSES + 2;   // 82
constexpr int MAX_OBJ = 32;
constexpr int LEVELS = 5;
constexpr int BINS = MAX_OBJ * LEVELS;    // 160
constexpr int BLK = 256;
constexpr int NBLK = (A_TOTAL + BLK - 1) / BLK;  // 22 blocks per batch

__device__ __forceinline__ int lev_of(int a) {
    return (a < 4096) ? 0 : (a < 5120) ? 1 : (a < 5376) ? 2 : (a < 5440) ? 3 : 4;
}

// One fused kernel. Phase 1 (all blocks): per-anchor loss -> per-block partial
// histogram + pos-mask output. Last-finishing block per batch (threadfence
// reduction pattern): reduce partials -> targets -> gather whole batch.
__global__ void __launch_bounds__(BLK)
fused_dwlm_kernel(const float* __restrict__ cls_pred,
                  const float* __restrict__ loc_pred,
                  const float* __restrict__ cls_tar,
                  const float* __restrict__ loc_tar,
                  const int*   __restrict__ ind_tar,
                  const int*   __restrict__ bbox_cnt,
                  float* __restrict__ p_sum,            // [B][NBLK][BINS]
                  float* __restrict__ p_cnt,            // [B][NBLK][BINS]
                  unsigned int* __restrict__ counters,  // [B], zeroed per launch
                  float* __restrict__ out) {
    __shared__ float s_sum[BINS];
    __shared__ float s_cnt[BINS];
    __shared__ float s_tgt[BINS];
    __shared__ int   s_last;
    const int t = threadIdx.x;
    for (int i = t; i < BINS; i += BLK) { s_sum[i] = 0.f; s_cnt[i] = 0.f; }
    __syncthreads();

    const int b = blockIdx.y;
    const int a = blockIdx.x * BLK + t;
    if (a < A_TOTAL) {
        const size_t row = (size_t)b * A_TOTAL + a;
        const float4* pred4 = (const float4*)(cls_pred + row * NUM_CLASSES); // 320B rows (64B-aligned)
        const float2* tar2  = (const float2*)(cls_tar  + row * NUM_CH);      // 328B rows (8B-aligned)
        float fl = 0.f;
        #pragma unroll 5
        for (int c = 0; c < NUM_CLASSES / 4; ++c) {
            float4 p4 = pred4[c];
            float2 ta = tar2[2 * c];
            float2 tb = tar2[2 * c + 1];
            float ps[4] = {p4.x, p4.y, p4.z, p4.w};
            float ts[4] = {ta.x, ta.y, tb.x, tb.y};
            #pragma unroll
            for (int j = 0; j < 4; ++j) {
                float p  = fminf(fmaxf(ps[j], 1e-7f), 1.0f - 1e-7f);
                float tt = ts[j];
                float ce = -(tt * __logf(p) + (1.f - tt) * __logf(1.f - p));
                float alpha_t = tt * 0.25f + (1.f - tt) * 0.75f;
                float pt = tt * (1.f - p) + (1.f - tt) * p;
                fl += alpha_t * pt * pt * ce;
            }
        }
        float pos = tar2[40].y;                   // channel 81, L1-hot
        out[(size_t)BATCH * A_TOTAL + row] = pos; // output 1: [B, A]

        float4 T = ((const float4*)(loc_tar  + row * 4))[0];
        float4 P = ((const float4*)(loc_pred + row * 4))[0];
        float area_t = (T.x + T.z) * (T.y + T.w);
        float area_p = (P.x + P.z) * (P.y + P.w);
        float inter  = (fminf(T.x, P.x) + fminf(T.z, P.z)) * (fminf(T.y, P.y) + fminf(T.w, P.w));
        float uni    = area_t + area_p - inter;
        float iou    = inter / fmaxf(uni, 1e-7f);
        float enc    = (fmaxf(T.x, P.x) + fmaxf(T.z, P.z)) * (fmaxf(T.y, P.y) + fmaxf(T.w, P.w));
        float giou   = iou - (enc - uni) / fmaxf(enc, 1e-7f);
        float loss   = fl + (1.f - giou);

        int bin = ind_tar[row] * LEVELS + lev_of(a);
        atomicAdd(&s_sum[bin], loss);
        atomicAdd(&s_cnt[bin], 1.0f);
    }
    __syncthreads();
    const size_t slot = ((size_t)b * NBLK + blockIdx.x) * BINS;
    for (int i = t; i < BINS; i += BLK) {
        p_sum[slot + i] = s_sum[i];
        p_cnt[slot + i] = s_cnt[i];
    }

    // -------- release partials + pos, then count this block done --------
    __threadfence();                 // all threads: make stores device-visible
    __syncthreads();                 // all stores of this block are issued+fenced
    if (t == 0) {
        unsigned int old = atomicAdd(&counters[b], 1u);
        s_last = (old == NBLK - 1);
    }
    __syncthreads();
    if (!s_last) return;

    // -------- tail: only the last block of batch b --------
    __threadfence();                 // acquire: invalidate caches before reading partials
    if (t < BINS) {
        float s = 0.f, c = 0.f;
        const size_t base = (size_t)b * NBLK * BINS + t;
        #pragma unroll
        for (int k = 0; k < NBLK; ++k) {
            s += p_sum[base + (size_t)k * BINS];
            c += p_cnt[base + (size_t)k * BINS];
        }
        s_sum[t] = s / fmaxf(1.0f, c);           // reuse s_sum as per-bin mean
    }
    if (t == 0) atomicExch(&counters[b], 0u);    // reset for next launch (deterministic replay)
    __syncthreads();

    if (t < MAX_OBJ) {
        float mean[LEVELS];
        float mx = -1e30f;
        #pragma unroll
        for (int l = 0; l < LEVELS; ++l) {
            mean[l] = s_sum[t * LEVELS + l];
            mx = fmaxf(mx, mean[l]);
        }
        float lmax = mx + 1e-5f;
        float mn = 1e30f;
        #pragma unroll
        for (int l = 0; l < LEVELS; ++l) {
            if (mean[l] == 0.0f) mean[l] = lmax;
            mn = fminf(mn, mean[l]);
        }
        float denom = lmax - mn;
        float tgt[LEVELS];
        float m1 = -1e30f, m2 = -1e30f, m3 = -1e30f;
        #pragma unroll
        for (int l = 0; l < LEVELS; ++l) {
            float v = 1.0f - (mean[l] - mn) / denom;
            tgt[l] = v;
            if (v > m1)      { m3 = m2; m2 = m1; m1 = v; }
            else if (v > m2) { m3 = m2; m2 = v; }
            else if (v > m3) { m3 = v; }
        }
        const bool valid = t < bbox_cnt[b];
        #pragma unroll
        for (int l = 0; l < LEVELS; ++l) {
            float v = tgt[l];
            v = (v >= m3) ? v : 0.0f;
            s_tgt[t * LEVELS + l] = valid ? v : 0.0f;
        }
    }
    __syncthreads();

    // gather the whole batch (coalesced; pos + ind are L2/L3-hot)
    for (int a2 = t; a2 < A_TOTAL; a2 += BLK) {
        const size_t row = (size_t)b * A_TOTAL + a2;
        float pos = out[(size_t)BATCH * A_TOTAL + row];
        int o = ind_tar[row];
        out[row] = (pos > 0.0f) ? s_tgt[o * LEVELS + lev_of(a2)] : 1.0f;
    }
}

extern "C" void kernel_launch(void* const* d_in, const int* in_sizes, int n_in,
                              void* d_out, int out_size, void* d_ws, size_t ws_size,
                              hipStream_t stream) {
    const float* cls_pred = (const float*)d_in[0];
    const float* loc_pred = (const float*)d_in[1];
    const float* cls_tar  = (const float*)d_in[2];
    const float* loc_tar  = (const float*)d_in[3];
    const int*   ind_tar  = (const int*)d_in[4];
    const int*   bbox_cnt = (const int*)d_in[5];
    float* out = (float*)d_out;

    float* p_sum = (float*)d_ws;                          // [16][22][160]
    float* p_cnt = p_sum + (size_t)BATCH * NBLK * BINS;
    unsigned int* counters = (unsigned int*)(p_cnt + (size_t)BATCH * NBLK * BINS);

    // counters must start at 0 every launch (d_ws is poisoned before timing)
    hipMemsetAsync(counters, 0, BATCH * sizeof(unsigned int), stream);

    fused_dwlm_kernel<<<dim3(NBLK, BATCH), dim3(BLK), 0, stream>>>(
        cls_pred, loc_pred, cls_tar, loc_tar, ind_tar, bbox_cnt,
        p_sum, p_cnt, counters, out);
}

// Round 5
// 50.315 us; speedup vs baseline: 1.6942x; 1.6942x over previous
//
#include <hip/hip_runtime.h>

constexpr int A_TOTAL = 5456;
constexpr int BATCH = 16;
constexpr int NUM_CLASSES = 80;
constexpr int NUM_CH = NUM_CLASSES + 2;   // 82
constexpr int MAX_OBJ = 32;
constexpr int LEVELS = 5;
constexpr int BINS = MAX_OBJ * LEVELS;    // 160
constexpr int BLK = 256;
constexpr int NBLK = (A_TOTAL + BLK - 1) / BLK;  // 22 blocks per batch

__device__ __forceinline__ int lev_of(int a) {
    return (a < 4096) ? 0 : (a < 5120) ? 1 : (a < 5376) ? 2 : (a < 5440) ? 3 : 4;
}

// Fused kernel, fence-free. All cross-block data moves through device-scope
// atomics (coherent at the LLC on MI355X; per-XCD L2 never holds it dirty):
//   phase 1: LDS hist -> global atomicAdd into [B][BINS] bins (zeroed per launch)
//   last block per batch: coherent bin reads via atomicAdd(p, 0.0f) -> targets
//   -> gather. pos read from read-only cls_tar (inputs never written).
__global__ void __launch_bounds__(BLK)
fused_dwlm_kernel(const float* __restrict__ cls_pred,
                  const float* __restrict__ loc_pred,
                  const float* __restrict__ cls_tar,
                  const float* __restrict__ loc_tar,
                  const int*   __restrict__ ind_tar,
                  const int*   __restrict__ bbox_cnt,
                  float* __restrict__ g_sum,            // [B][BINS] zeroed per launch
                  float* __restrict__ g_cnt,            // [B][BINS] zeroed per launch
                  unsigned int* __restrict__ counters,  // [B]       zeroed per launch
                  float* __restrict__ out) {
    __shared__ float s_sum[BINS];
    __shared__ float s_cnt[BINS];
    __shared__ float s_tgt[BINS];
    __shared__ int   s_last;
    const int t = threadIdx.x;
    for (int i = t; i < BINS; i += BLK) { s_sum[i] = 0.f; s_cnt[i] = 0.f; }
    __syncthreads();

    const int b = blockIdx.y;
    const int a = blockIdx.x * BLK + t;
    if (a < A_TOTAL) {
        const size_t row = (size_t)b * A_TOTAL + a;
        const float4* pred4 = (const float4*)(cls_pred + row * NUM_CLASSES); // 320B rows
        const float2* tar2  = (const float2*)(cls_tar  + row * NUM_CH);      // 328B rows
        float fl = 0.f;
        #pragma unroll 5
        for (int c = 0; c < NUM_CLASSES / 4; ++c) {
            float4 p4 = pred4[c];
            float2 ta = tar2[2 * c];
            float2 tb = tar2[2 * c + 1];
            float ps[4] = {p4.x, p4.y, p4.z, p4.w};
            float ts[4] = {ta.x, ta.y, tb.x, tb.y};
            #pragma unroll
            for (int j = 0; j < 4; ++j) {
                float p  = fminf(fmaxf(ps[j], 1e-7f), 1.0f - 1e-7f);
                float tt = ts[j];
                float ce = -(tt * __logf(p) + (1.f - tt) * __logf(1.f - p));
                float alpha_t = tt * 0.25f + (1.f - tt) * 0.75f;
                float pt = tt * (1.f - p) + (1.f - tt) * p;
                fl += alpha_t * pt * pt * ce;
            }
        }
        float pos = tar2[40].y;                   // channel 81, L1-hot
        out[(size_t)BATCH * A_TOTAL + row] = pos; // output 1: [B, A] (host-read only)

        float4 T = ((const float4*)(loc_tar  + row * 4))[0];
        float4 P = ((const float4*)(loc_pred + row * 4))[0];
        float area_t = (T.x + T.z) * (T.y + T.w);
        float area_p = (P.x + P.z) * (P.y + P.w);
        float inter  = (fminf(T.x, P.x) + fminf(T.z, P.z)) * (fminf(T.y, P.y) + fminf(T.w, P.w));
        float uni    = area_t + area_p - inter;
        float iou    = inter / fmaxf(uni, 1e-7f);
        float enc    = (fmaxf(T.x, P.x) + fmaxf(T.z, P.z)) * (fmaxf(T.y, P.y) + fmaxf(T.w, P.w));
        float giou   = iou - (enc - uni) / fmaxf(enc, 1e-7f);
        float loss   = fl + (1.f - giou);

        int bin = ind_tar[row] * LEVELS + lev_of(a);
        atomicAdd(&s_sum[bin], loss);
        atomicAdd(&s_cnt[bin], 1.0f);
    }
    __syncthreads();

    // flush LDS histogram to global bins (device-scope atomics, coherent)
    for (int i = t; i < BINS; i += BLK) {
        float c = s_cnt[i];
        if (c != 0.f) {
            atomicAdd(&g_sum[b * BINS + i], s_sum[i]);
            atomicAdd(&g_cnt[b * BINS + i], c);
        }
    }
    // __syncthreads() drains each thread's outstanding vmem (compiler emits
    // s_waitcnt vmcnt(0) before s_barrier) -> bin atomics are complete at the
    // coherent point before the counter increment below. No fence needed.
    __syncthreads();
    if (t == 0) {
        unsigned int old = atomicAdd(&counters[b], 1u);
        s_last = (old == NBLK - 1);
    }
    __syncthreads();
    if (!s_last) return;

    // -------- tail: only the last-finishing block of batch b --------
    if (t < BINS) {
        float s = atomicAdd(&g_sum[b * BINS + t], 0.0f);  // coherent RMW read
        float c = atomicAdd(&g_cnt[b * BINS + t], 0.0f);
        s_sum[t] = s / fmaxf(1.0f, c);                    // reuse s_sum as mean
    }
    __syncthreads();

    if (t < MAX_OBJ) {
        float mean[LEVELS];
        float mx = -1e30f;
        #pragma unroll
        for (int l = 0; l < LEVELS; ++l) {
            mean[l] = s_sum[t * LEVELS + l];
            mx = fmaxf(mx, mean[l]);
        }
        float lmax = mx + 1e-5f;
        float mn = 1e30f;
        #pragma unroll
        for (int l = 0; l < LEVELS; ++l) {
            if (mean[l] == 0.0f) mean[l] = lmax;
            mn = fminf(mn, mean[l]);
        }
        float denom = lmax - mn;
        float tgt[LEVELS];
        float m1 = -1e30f, m2 = -1e30f, m3 = -1e30f;
        #pragma unroll
        for (int l = 0; l < LEVELS; ++l) {
            float v = 1.0f - (mean[l] - mn) / denom;
            tgt[l] = v;
            if (v > m1)      { m3 = m2; m2 = m1; m1 = v; }
            else if (v > m2) { m3 = m2; m2 = v; }
            else if (v > m3) { m3 = v; }
        }
        const bool valid = t < bbox_cnt[b];
        #pragma unroll
        for (int l = 0; l < LEVELS; ++l) {
            float v = tgt[l];
            v = (v >= m3) ? v : 0.0f;
            s_tgt[t * LEVELS + l] = valid ? v : 0.0f;
        }
    }
    __syncthreads();

    // gather the whole batch; pos from read-only cls_tar (L3-hot), ind coalesced
    for (int a2 = t; a2 < A_TOTAL; a2 += BLK) {
        const size_t row = (size_t)b * A_TOTAL + a2;
        float pos = cls_tar[row * NUM_CH + (NUM_CH - 1)];
        int o = ind_tar[row];
        out[row] = (pos > 0.0f) ? s_tgt[o * LEVELS + lev_of(a2)] : 1.0f;
    }
}

extern "C" void kernel_launch(void* const* d_in, const int* in_sizes, int n_in,
                              void* d_out, int out_size, void* d_ws, size_t ws_size,
                              hipStream_t stream) {
    const float* cls_pred = (const float*)d_in[0];
    const float* loc_pred = (const float*)d_in[1];
    const float* cls_tar  = (const float*)d_in[2];
    const float* loc_tar  = (const float*)d_in[3];
    const int*   ind_tar  = (const int*)d_in[4];
    const int*   bbox_cnt = (const int*)d_in[5];
    float* out = (float*)d_out;

    float* g_sum = (float*)d_ws;                            // [16][160]
    float* g_cnt = g_sum + (size_t)BATCH * BINS;            // [16][160]
    unsigned int* counters = (unsigned int*)(g_cnt + (size_t)BATCH * BINS);  // [16]

    // zero bins + counters each launch (captured into the graph, replayed)
    hipMemsetAsync(d_ws, 0, (2 * BATCH * BINS) * sizeof(float) + BATCH * sizeof(unsigned int), stream);

    fused_dwlm_kernel<<<dim3(NBLK, BATCH), dim3(BLK), 0, stream>>>(
        cls_pred, loc_pred, cls_tar, loc_tar, ind_tar, bbox_cnt,
        g_sum, g_cnt, counters, out);
}

// Round 6
// 23.488 us; speedup vs baseline: 3.6294x; 2.1422x over previous
//
#include <hip/hip_runtime.h>

constexpr int A_TOTAL = 5456;
constexpr int BATCH = 16;
constexpr int NUM_CLASSES = 80;
constexpr int NUM_CH = NUM_CLASSES + 2;   // 82
constexpr int MAX_OBJ = 32;
constexpr int LEVELS = 5;
constexpr int BINS = MAX_OBJ * LEVELS;    // 160
constexpr int BLK_L = 1024;                         // loss kernel block (16 waves)
constexpr int APB = BLK_L / 4;                      // 256 anchors per block (QPR=4)
constexpr int NBLK = (A_TOTAL + APB - 1) / APB;     // 22 blocks per batch
constexpr int BLK_G = 256;                          // gather kernel block

__device__ __forceinline__ int lev_of(int a) {
    return (a < 4096) ? 0 : (a < 5120) ? 1 : (a < 5376) ? 2 : (a < 5440) ? 3 : 4;
}

// Kernel A: 4 lanes per anchor row (20 classes each; each 4-lane cluster's
// float4 loads form one full 64B line -> perfect per-instruction coalescing).
// 1024-thread blocks give 16 waves/block, ~22 waves/CU (vs 5.5 in R2) for
// latency hiding. Per-block partial histograms as in R2 (22 slots, no atomics,
// no zero-init). Lane q==0 of each cluster adds GIoU, histograms, writes pos.
__global__ void __launch_bounds__(BLK_L)
loss_accum_kernel(const float* __restrict__ cls_pred,
                  const float* __restrict__ loc_pred,
                  const float* __restrict__ cls_tar,
                  const float* __restrict__ loc_tar,
                  const int*   __restrict__ ind_tar,
                  float* __restrict__ p_sum,   // [B][NBLK][BINS]
                  float* __restrict__ p_cnt,   // [B][NBLK][BINS]
                  float* __restrict__ out) {
    __shared__ float s_sum[BINS];
    __shared__ float s_cnt[BINS];
    const int t = threadIdx.x;
    if (t < BINS) { s_sum[t] = 0.f; s_cnt[t] = 0.f; }
    __syncthreads();

    const int b = blockIdx.y;
    const int a = blockIdx.x * APB + (t >> 2);  // anchor row
    const int q = t & 3;                        // quarter-row id
    const bool valid = a < A_TOTAL;

    float fl = 0.f;
    size_t row = 0;
    if (valid) {
        row = (size_t)b * A_TOTAL + a;
        // elements 4q+16j+{0..3}: cluster covers classes 0..79 exactly
        const float4* pred4 = (const float4*)cls_pred + row * 20 + q;
        const float2* tar2  = (const float2*)cls_tar  + row * 41 + 2 * q;
        #pragma unroll
        for (int j = 0; j < 5; ++j) {
            float4 p4 = pred4[4 * j];
            float2 ta = tar2[8 * j];
            float2 tb = tar2[8 * j + 1];
            float ps[4] = {p4.x, p4.y, p4.z, p4.w};
            float ts[4] = {ta.x, ta.y, tb.x, tb.y};
            #pragma unroll
            for (int k = 0; k < 4; ++k) {
                float p  = fminf(fmaxf(ps[k], 1e-7f), 1.0f - 1e-7f);
                float tt = ts[k];
                float ce = -(tt * __logf(p) + (1.f - tt) * __logf(1.f - p));
                float alpha_t = tt * 0.25f + (1.f - tt) * 0.75f;
                float pt = tt * (1.f - p) + (1.f - tt) * p;
                fl += alpha_t * pt * pt * ce;
            }
        }
    }
    // reduce the 4 quarter-row partials (clusters are wave-aligned)
    fl += __shfl_xor(fl, 1);
    fl += __shfl_xor(fl, 2);

    if (valid && q == 0) {
        // channel 81: line is covered by neighbor rows' class loads (L1/L2-hot)
        float pos = cls_tar[row * NUM_CH + (NUM_CH - 1)];
        out[(size_t)BATCH * A_TOTAL + row] = pos;   // output 1: [B, A]

        float4 T = ((const float4*)(loc_tar  + row * 4))[0];
        float4 P = ((const float4*)(loc_pred + row * 4))[0];
        float area_t = (T.x + T.z) * (T.y + T.w);
        float area_p = (P.x + P.z) * (P.y + P.w);
        float inter  = (fminf(T.x, P.x) + fminf(T.z, P.z)) * (fminf(T.y, P.y) + fminf(T.w, P.w));
        float uni    = area_t + area_p - inter;
        float iou    = inter / fmaxf(uni, 1e-7f);
        float enc    = (fmaxf(T.x, P.x) + fmaxf(T.z, P.z)) * (fmaxf(T.y, P.y) + fmaxf(T.w, P.w));
        float giou   = iou - (enc - uni) / fmaxf(enc, 1e-7f);
        float loss   = fl + (1.f - giou);

        int bin = ind_tar[row] * LEVELS + lev_of(a);
        atomicAdd(&s_sum[bin], loss);
        atomicAdd(&s_cnt[bin], 1.0f);
    }
    __syncthreads();
    const size_t slot = ((size_t)b * NBLK + blockIdx.x) * BINS;
    if (t < BINS) {
        p_sum[slot + t] = s_sum[t];
        p_cnt[slot + t] = s_cnt[t];
    }
}

// Kernel B (R2-proven): reduce partials (redundantly per block, L2-hot) ->
// per-(o,l) target -> gather, pos staged in d_out by kernel A.
__global__ void __launch_bounds__(BLK_G)
gather_kernel(const float* __restrict__ p_sum,
              const float* __restrict__ p_cnt,
              const int*   __restrict__ ind_tar,
              const int*   __restrict__ bbox_cnt,
              float* __restrict__ out) {
    __shared__ float s_mean[BINS];
    __shared__ float s_tgt[BINS];
    const int t = threadIdx.x;
    const int b = blockIdx.y;

    if (t < BINS) {
        float s = 0.f, c = 0.f;
        const size_t base = (size_t)b * NBLK * BINS + t;
        #pragma unroll
        for (int k = 0; k < NBLK; ++k) {
            s += p_sum[base + (size_t)k * BINS];
            c += p_cnt[base + (size_t)k * BINS];
        }
        s_mean[t] = s / fmaxf(1.0f, c);
    }
    __syncthreads();

    if (t < MAX_OBJ) {
        float mean[LEVELS];
        float mx = -1e30f;
        #pragma unroll
        for (int l = 0; l < LEVELS; ++l) {
            mean[l] = s_mean[t * LEVELS + l];
            mx = fmaxf(mx, mean[l]);
        }
        float lmax = mx + 1e-5f;
        float mn = 1e30f;
        #pragma unroll
        for (int l = 0; l < LEVELS; ++l) {
            if (mean[l] == 0.0f) mean[l] = lmax;
            mn = fminf(mn, mean[l]);
        }
        float denom = lmax - mn;
        float tgt[LEVELS];
        float m1 = -1e30f, m2 = -1e30f, m3 = -1e30f;
        #pragma unroll
        for (int l = 0; l < LEVELS; ++l) {
            float v = 1.0f - (mean[l] - mn) / denom;
            tgt[l] = v;
            if (v > m1)      { m3 = m2; m2 = m1; m1 = v; }
            else if (v > m2) { m3 = m2; m2 = v; }
            else if (v > m3) { m3 = v; }
        }
        const bool valid = t < bbox_cnt[b];
        #pragma unroll
        for (int l = 0; l < LEVELS; ++l) {
            float v = tgt[l];
            v = (v >= m3) ? v : 0.0f;
            s_tgt[t * LEVELS + l] = valid ? v : 0.0f;
        }
    }
    __syncthreads();

    const int a = blockIdx.x * BLK_G + t;
    if (a >= A_TOTAL) return;
    const size_t row = (size_t)b * A_TOTAL + a;
    float pos = out[(size_t)BATCH * A_TOTAL + row];  // staged by kernel A (dense)
    int o = ind_tar[row];
    out[row] = (pos > 0.0f) ? s_tgt[o * LEVELS + lev_of(a)] : 1.0f;
}

extern "C" void kernel_launch(void* const* d_in, const int* in_sizes, int n_in,
                              void* d_out, int out_size, void* d_ws, size_t ws_size,
                              hipStream_t stream) {
    const float* cls_pred = (const float*)d_in[0];
    const float* loc_pred = (const float*)d_in[1];
    const float* cls_tar  = (const float*)d_in[2];
    const float* loc_tar  = (const float*)d_in[3];
    const int*   ind_tar  = (const int*)d_in[4];
    const int*   bbox_cnt = (const int*)d_in[5];
    float* out = (float*)d_out;

    float* p_sum = (float*)d_ws;                       // [16][22][160]
    float* p_cnt = p_sum + (size_t)BATCH * NBLK * BINS;

    loss_accum_kernel<<<dim3(NBLK, BATCH), dim3(BLK_L), 0, stream>>>(
        cls_pred, loc_pred, cls_tar, loc_tar, ind_tar, p_sum, p_cnt, out);
    gather_kernel<<<dim3((A_TOTAL + BLK_G - 1) / BLK_G, BATCH), dim3(BLK_G), 0, stream>>>(
        p_sum, p_cnt, ind_tar, bbox_cnt, out);
}